// Round 18
// baseline (146.740 us; speedup 1.0000x reference)
//
#include <hip/hip_runtime.h>
#include <hip/hip_bf16.h>

typedef unsigned short u16;
typedef unsigned int u32;

#define THREADS 512
constexpr int CH = 64;        // in/out channels
constexpr int PP = 32;        // neighbors per point
constexpr int TM = 16;        // points per tile
constexpr int GRID = 625;     // persistent blocks: 3125 tiles / 5 each, balanced

// ---- LDS layout (bytes) ----
// W:  [16 m][16 g][32 p] bf16, A-fragment order = 16384
// Mb: [16 pt][1024 k] bf16, XOR-swizzled (byte ^= ((m&7)^(g&7))<<4) = 32768
// Rb: 4 KB f32 split-k partials (de-aliased: no extra barrier per iter)
constexpr int W_OFF  = 0;
constexpr int MB_OFF = 16384;
constexpr int RB_OFF = 49152;
constexpr int LDS_BYTES = 53248;   // x3 = 156 KB -> 3 blocks/CU

typedef __attribute__((ext_vector_type(8))) short short8;
typedef __attribute__((ext_vector_type(4))) float f32x4;

static __device__ __forceinline__ u16 f2bf_rne(float f) {
  __hip_bfloat16 h = __float2bfloat16(f);
  return __builtin_bit_cast(u16, h);
}
static __device__ __forceinline__ u16 rbf(float f) {  // cheap round-half-up (2 VALU)
  u32 u = __builtin_bit_cast(u32, f);
  return (u16)((u + 0x8000u) >> 16);
}

// ---- merged prep ----
// features f32 -> bf16 in CHANNEL-INTERLEAVED row layout:
//   row r, qword slot l15 (8B) = channels { l15, l15+16, l15+32, l15+48 }
// kernel f32 [g][i][o] -> bf16 in B-fragment order
__global__ void prep_all(const float* __restrict__ feat, u16* __restrict__ fbf,
                         const float* __restrict__ kern, u16* __restrict__ k2f,
                         int nq) {
  int i = blockIdx.x * blockDim.x + threadIdx.x;
  if (i < nq) {                       // nq = N*16 qwords
    const int row = i >> 4, l15 = i & 15;
    const float* src = feat + (size_t)row * 64 + l15;
    const u32 a0 = f2bf_rne(src[0]);
    const u32 a1 = f2bf_rne(src[16]);
    const u32 a2 = f2bf_rne(src[32]);
    const u32 a3 = f2bf_rne(src[48]);
    uint2 w; w.x = a0 | (a1 << 16); w.y = a2 | (a3 << 16);
    ((uint2*)fbf)[i] = w;
  } else {
    const int d = i - nq;
    if (d < 65536) {
      const int e = d & 7, l = (d >> 3) & 63, ot = (d >> 9) & 3, ks = d >> 11;
      const int k = ks * 32 + (l >> 4) * 8 + e;
      const int o = ot * 16 + (l & 15);
      k2f[d] = f2bf_rne(kern[k * 64 + o]);
    }
  }
}

// ---- main fused kernel: persistent, 5 tiles of 16 points per block, 8 waves ----
__global__ __launch_bounds__(THREADS, 4) void cconv_main(
    const int* __restrict__ recv, const float* __restrict__ relpos,
    const float* __restrict__ wsup, const int* __restrict__ aptr,
    const u16* __restrict__ fbf, const u16* __restrict__ k2f,
    const float* __restrict__ bias, float* __restrict__ out, int ntile) {
  __shared__ __align__(16) char smem[LDS_BYTES];
  const int tid = threadIdx.x;
  const int wid = tid >> 6, lane = tid & 63;
  const int l15 = lane & 15, l4 = lane >> 4;
  const int pairp = wid & 3;    // o-tile (o = pairp*16 + l15)
  const int half  = wid >> 2;   // split-k half (ks = half*16 + j)
  const char* fb2 = (const char*)fbf;

  // ---- persistent B-slice: this wave's 16 k2f fragments held in registers ----
  short8 b2r[16];
  #pragma unroll
  for (int j = 0; j < 16; ++j)
    b2r[j] = *(const short8*)(k2f +
        ((u32)((half * 16 + j) * 4 + pairp) * 64u + (u32)lane) * 8u);

  const float invws = 1.0f / wsup[0];
  int aexp = aptr[0];
  if (aexp < 0 || aexp > 64) aexp = (int)(*(const float*)aptr);  // dtype fallback
  const float bv = bias[pairp * 16 + l15];

  for (int tile = blockIdx.x; tile < ntile; tile += GRID) {
    const int n0 = tile * TM;

    // ---- gather: receiver ids + 16 feature dwordx2 loads (both points) ----
    const int* rp0 = recv + (n0 + wid * 2) * PP + l4 * 8;
    const int4 A40 = *(const int4*)rp0;
    const int4 B40 = *(const int4*)(rp0 + 4);
    const int4 A41 = *(const int4*)(rp0 + PP);
    const int4 B41 = *(const int4*)(rp0 + PP + 4);
    const int rv0[8] = {A40.x, A40.y, A40.z, A40.w, B40.x, B40.y, B40.z, B40.w};
    const int rv1[8] = {A41.x, A41.y, A41.z, A41.w, B41.x, B41.y, B41.z, B41.w};
    uint2 q20[8], q21[8];
    #pragma unroll
    for (int e = 0; e < 8; ++e)
      q20[e] = *(const uint2*)(fb2 + (size_t)(u32)rv0[e] * 128u + (u32)l15 * 8u);
    #pragma unroll
    for (int e = 0; e < 8; ++e)
      q21[e] = *(const uint2*)(fb2 + (size_t)(u32)rv1[e] * 128u + (u32)l15 * 8u);

    // ---- P0: W for this wave's 2 points -> LDS, A-fragment order [m][g][p] ----
    // tid>>5 == m: W[2wid], W[2wid+1] written ONLY by this wave -> no barrier.
    {
      const int e = tid;
      const int m = e >> 5, p = e & 31;
      const int ei = (n0 + m) * PP + p;
      const float2 rp2 = ((const float2*)relpos)[ei];
      const float rx = rp2.x * invws, ry = rp2.y * invws;
      const float d2 = rx * rx + ry * ry;
      const float w1 = fmaxf(1.0f - d2, 0.0f);
      float win = 1.0f;
      for (int q = 0; q < aexp; ++q) win *= w1;
      float gy = fminf(fmaxf((rx + 1.0f) * 1.5f, 0.0f), 3.0f);
      float gx = fminf(fmaxf((ry + 1.0f) * 1.5f, 0.0f), 3.0f);
      int y0 = (int)gy; y0 = y0 > 2 ? 2 : y0;
      int x0 = (int)gx; x0 = x0 > 2 ? 2 : x0;
      const float fy = gy - (float)y0, fx = gx - (float)x0;
      u16* wp = (u16*)(smem + W_OFF) + m * 512 + p;
      #pragma unroll
      for (int g = 0; g < 16; ++g) {
        const int y = g >> 2, x = g & 3;
        const float wyv = (y == y0) ? (1.0f - fy) : (y == y0 + 1) ? fy : 0.0f;
        const float wxv = (x == x0) ? (1.0f - fx) : (x == x0 + 1) ? fx : 0.0f;
        wp[g * 32] = rbf(win * wyv * wxv);
      }
    }

    // ---- build: this wave's 2 points into Mb[16 pts] ----
    #pragma unroll
    for (int t = 0; t < 2; ++t) {
      const int m = wid * 2 + t;
      const short8 af = *(const short8*)(smem + W_OFF + m * 1024 + l15 * 64 + l4 * 16);
      const uint2* q2 = (t == 0) ? q20 : q21;
      f32x4 accm[4];
      const f32x4 cz = {0.f, 0.f, 0.f, 0.f};
      union { u32 u[4]; short8 s; } bb;
      #pragma unroll
      for (int j = 0; j < 4; ++j)
        bb.u[j] = (q2[2 * j].x & 0xffffu) | (q2[2 * j + 1].x << 16);
      accm[0] = __builtin_amdgcn_mfma_f32_16x16x32_bf16(af, bb.s, cz, 0, 0, 0);
      #pragma unroll
      for (int j = 0; j < 4; ++j)
        bb.u[j] = (q2[2 * j].x >> 16) | (q2[2 * j + 1].x & 0xffff0000u);
      accm[1] = __builtin_amdgcn_mfma_f32_16x16x32_bf16(af, bb.s, cz, 0, 0, 0);
      #pragma unroll
      for (int j = 0; j < 4; ++j)
        bb.u[j] = (q2[2 * j].y & 0xffffu) | (q2[2 * j + 1].y << 16);
      accm[2] = __builtin_amdgcn_mfma_f32_16x16x32_bf16(af, bb.s, cz, 0, 0, 0);
      #pragma unroll
      for (int j = 0; j < 4; ++j)
        bb.u[j] = (q2[2 * j].y >> 16) | (q2[2 * j + 1].y & 0xffff0000u);
      accm[3] = __builtin_amdgcn_mfma_f32_16x16x32_bf16(af, bb.s, cz, 0, 0, 0);
      #pragma unroll
      for (int ib = 0; ib < 4; ++ib)
        #pragma unroll
        for (int r = 0; r < 4; ++r) {
          const int g = l4 * 4 + r;
          const u32 k = (u32)(g * 64 + ib * 16 + l15);
          u32 byt = (u32)m * 2048u + k * 2u;
          byt ^= ((u32)((m & 7) ^ (g & 7)) << 4);
          *(u16*)(smem + MB_OFF + byt) = rbf(accm[ib][r]);
        }
    }
    __syncthreads();   // BAR1: Mb complete

    // ---- split-k GEMM2: b2 from registers, a2 from LDS ----
    f32x4 acc = {0.f, 0.f, 0.f, 0.f};
    {
      const u32 rowb = (u32)l15 * 2048u;
      const u32 swl = (u32)(l15 & 7) << 4;
      #pragma unroll
      for (int j = 0; j < 16; ++j) {
        const int ks = half * 16 + j;
        const u32 kc = (u32)ks * 32u + (u32)l4 * 8u;
        const u32 g7 = (((kc >> 6) & 7u) << 4);
        const u32 byt = (rowb + kc * 2u) ^ swl ^ g7;
        const short8 a2 = *(const short8*)(smem + MB_OFF + byt);
        acc = __builtin_amdgcn_mfma_f32_16x16x32_bf16(a2, b2r[j], acc, 0, 0, 0);
        if ((j & 1) == 1) __builtin_amdgcn_sched_barrier(0);  // anti-hoist (reg cap)
      }
    }

    // ---- split-k partials through Rb (dedicated region) ----
    if (half == 1) {
      #pragma unroll
      for (int r = 0; r < 4; ++r) {
        const int row = l4 * 4 + r;
        const u32 byt = (u32)pairp * 1024u + (u32)row * 64u + (u32)((l15 ^ l4) * 4);
        *(float*)(smem + RB_OFF + byt) = acc[r];
      }
    }
    __syncthreads();   // BAR2: partials visible; Mb reads done (next build safe)
    if (half == 0) {
      #pragma unroll
      for (int r = 0; r < 4; ++r) {
        const int row = l4 * 4 + r;
        const u32 byt = (u32)pairp * 1024u + (u32)row * 64u + (u32)((l15 ^ l4) * 4);
        acc[r] += *(const float*)(smem + RB_OFF + byt);
      }
      const int o = pairp * 16 + l15;
      #pragma unroll
      for (int r = 0; r < 4; ++r)
        out[(n0 + l4 * 4 + r) * CH + o] = acc[r] * (1.0f / 32.0f) + bv;
    }
    // Rb read (above) precedes next Rb write (after next BAR1): race-free.
  }
}

extern "C" void kernel_launch(void* const* d_in, const int* in_sizes, int n_in,
                              void* d_out, int out_size, void* d_ws, size_t ws_size,
                              hipStream_t stream) {
  const float* features = (const float*)d_in[0];
  const int* receivers  = (const int*)d_in[1];
  const float* relpos   = (const float*)d_in[2];
  const float* wsup     = (const float*)d_in[3];
  const int* aptr       = (const int*)d_in[4];
  const float* kern     = (const float*)d_in[5];
  const float* bias     = (const float*)d_in[6];
  float* out = (float*)d_out;

  const int N = in_sizes[0] / CH;   // 50000
  u16* fbf = (u16*)d_ws;                                    // N*64 bf16, interleaved
  u16* k2f = (u16*)((char*)d_ws + (size_t)N * CH * 2);      // 128 KB, frag-ordered

  const int nq = N * 16;                                    // qwords of fbf
  const int prep_total = nq + 65536;
  prep_all<<<dim3((prep_total + 255) / 256), dim3(256), 0, stream>>>(
      features, fbf, kern, k2f, nq);

  const int ntile = N / TM;                                 // 3125
  cconv_main<<<dim3(GRID), dim3(THREADS), 0, stream>>>(
      receivers, relpos, wsup, aptr, fbf, k2f, bias, out, ntile);
}

// Round 19
// 48.509 us; speedup vs baseline: 3.0250x; 3.0250x over previous
//
#include <hip/hip_runtime.h>
#include <hip/hip_bf16.h>

typedef unsigned short u16;
typedef unsigned int u32;

#define THREADS 512
constexpr int CH = 64;        // in/out channels
constexpr int PP = 32;        // neighbors per point
constexpr int TM = 16;        // points per block

// ---- LDS layout (bytes) ----
// W:  [16 m][16 g][32 p] bf16, A-fragment order = 16384   (dead after build)
// Rb: 4 KB f32 split-k partials, aliases W region (safe: written only after
//     the build->GEMM2 barrier, which orders all W reads first)
// Mb: [16 pt][1024 k] bf16, XOR-swizzled (byte ^= ((m&7)^(g&7))<<4) = 32768
constexpr int W_OFF  = 0;
constexpr int RB_OFF = 0;
constexpr int MB_OFF = 16384;
constexpr int LDS_BYTES = 49152;   // 3 blocks/CU at 160 KiB, 24 waves/CU

typedef __attribute__((ext_vector_type(8))) short short8;
typedef __attribute__((ext_vector_type(4))) float f32x4;

static __device__ __forceinline__ u16 f2bf_rne(float f) {
  __hip_bfloat16 h = __float2bfloat16(f);
  return __builtin_bit_cast(u16, h);
}
static __device__ __forceinline__ u16 rbf(float f) {  // cheap round-half-up (2 VALU)
  u32 u = __builtin_bit_cast(u32, f);
  return (u16)((u + 0x8000u) >> 16);
}

// ---- merged prep ----
// features f32 -> bf16 in CHANNEL-INTERLEAVED row layout:
//   row r, qword slot l15 (8B) = channels { l15, l15+16, l15+32, l15+48 }
// kernel f32 [g][i][o] -> bf16 in B-fragment order
__global__ void prep_all(const float* __restrict__ feat, u16* __restrict__ fbf,
                         const float* __restrict__ kern, u16* __restrict__ k2f,
                         int nq) {
  int i = blockIdx.x * blockDim.x + threadIdx.x;
  if (i < nq) {                       // nq = N*16 qwords
    const int row = i >> 4, l15 = i & 15;
    const float* src = feat + (size_t)row * 64 + l15;
    const u32 a0 = f2bf_rne(src[0]);
    const u32 a1 = f2bf_rne(src[16]);
    const u32 a2 = f2bf_rne(src[32]);
    const u32 a3 = f2bf_rne(src[48]);
    uint2 w; w.x = a0 | (a1 << 16); w.y = a2 | (a3 << 16);
    ((uint2*)fbf)[i] = w;
  } else {
    const int d = i - nq;
    if (d < 65536) {
      const int e = d & 7, l = (d >> 3) & 63, ot = (d >> 9) & 3, ks = d >> 11;
      const int k = ks * 32 + (l >> 4) * 8 + e;
      const int o = ot * 16 + (l & 15);
      k2f[d] = f2bf_rne(kern[k * 64 + o]);
    }
  }
}

// ---- main fused kernel: 16 points per block, 8 waves, 3 blocks/CU ----
__global__ __launch_bounds__(THREADS, 6) void cconv_main(
    const int* __restrict__ recv, const float* __restrict__ relpos,
    const float* __restrict__ wsup, const int* __restrict__ aptr,
    const u16* __restrict__ fbf, const u16* __restrict__ k2f,
    const float* __restrict__ bias, float* __restrict__ out) {
  __shared__ __align__(16) char smem[LDS_BYTES];
  const int tid = threadIdx.x;
  const int n0 = blockIdx.x * TM;
  const int wid = tid >> 6, lane = tid & 63;
  const int l15 = lane & 15, l4 = lane >> 4;
  const int pairp = wid & 3;    // o-tile (o = pairp*16 + l15)
  const int half  = wid >> 2;   // split-k half (ks = half*16 + j)
  const char* fb2 = (const char*)fbf;

  // ---- issue-early: receiver ids + all 16 feature dwordx2 loads (both points) ----
  const int* rp0 = recv + (n0 + wid * 2) * PP + l4 * 8;
  const int4 A40 = *(const int4*)rp0;
  const int4 B40 = *(const int4*)(rp0 + 4);
  const int4 A41 = *(const int4*)(rp0 + PP);
  const int4 B41 = *(const int4*)(rp0 + PP + 4);
  const int rv0[8] = {A40.x, A40.y, A40.z, A40.w, B40.x, B40.y, B40.z, B40.w};
  const int rv1[8] = {A41.x, A41.y, A41.z, A41.w, B41.x, B41.y, B41.z, B41.w};
  uint2 q20[8], q21[8];
  #pragma unroll
  for (int e = 0; e < 8; ++e)
    q20[e] = *(const uint2*)(fb2 + (size_t)(u32)rv0[e] * 128u + (u32)l15 * 8u);
  #pragma unroll
  for (int e = 0; e < 8; ++e)
    q21[e] = *(const uint2*)(fb2 + (size_t)(u32)rv1[e] * 128u + (u32)l15 * 8u);

  // ---- P0: W for this wave's 2 points -> LDS in A-fragment order [m][g][p] ----
  // tid>>5 == m, so W[2wid], W[2wid+1] are written ONLY by this wave: no barrier
  // before build — same-wave LDS ordering (compiler lgkmcnt) suffices.
  {
    const float invws = 1.0f / wsup[0];
    int a = aptr[0];
    if (a < 0 || a > 64) a = (int)(*(const float*)aptr);  // dtype fallback
    const int e = tid;                 // 512 threads = 512 edges
    const int m = e >> 5, p = e & 31;
    const int ei = (n0 + m) * PP + p;
    const float2 rp2 = ((const float2*)relpos)[ei];
    const float rx = rp2.x * invws, ry = rp2.y * invws;
    const float d2 = rx * rx + ry * ry;
    const float w1 = fmaxf(1.0f - d2, 0.0f);
    float win = 1.0f;
    for (int q = 0; q < a; ++q) win *= w1;
    float gy = fminf(fmaxf((rx + 1.0f) * 1.5f, 0.0f), 3.0f);
    float gx = fminf(fmaxf((ry + 1.0f) * 1.5f, 0.0f), 3.0f);
    int y0 = (int)gy; y0 = y0 > 2 ? 2 : y0;
    int x0 = (int)gx; x0 = x0 > 2 ? 2 : x0;
    const float fy = gy - (float)y0, fx = gx - (float)x0;
    u16* wp = (u16*)(smem + W_OFF) + m * 512 + p;   // elem [m][g][p] = m*512 + g*32 + p
    #pragma unroll
    for (int g = 0; g < 16; ++g) {
      const int y = g >> 2, x = g & 3;
      const float wyv = (y == y0) ? (1.0f - fy) : (y == y0 + 1) ? fy : 0.0f;
      const float wxv = (x == x0) ? (1.0f - fx) : (x == x0 + 1) ? fx : 0.0f;
      wp[g * 32] = rbf(win * wyv * wxv);
    }
  }
  // NO __syncthreads() here (P0->build is wave-local)

  // ---- build phase: this wave's 2 points into Mb[16 pts] ----
  #pragma unroll
  for (int t = 0; t < 2; ++t) {
    const int m = wid * 2 + t;
    const short8 af = *(const short8*)(smem + W_OFF + m * 1024 + l15 * 64 + l4 * 16);
    const uint2* q2 = (t == 0) ? q20 : q21;
    f32x4 accm[4];
    const f32x4 cz = {0.f, 0.f, 0.f, 0.f};
    union { u32 u[4]; short8 s; } bb;
    // ib0: lows of .x
    #pragma unroll
    for (int j = 0; j < 4; ++j)
      bb.u[j] = (q2[2 * j].x & 0xffffu) | (q2[2 * j + 1].x << 16);
    accm[0] = __builtin_amdgcn_mfma_f32_16x16x32_bf16(af, bb.s, cz, 0, 0, 0);
    // ib1: highs of .x
    #pragma unroll
    for (int j = 0; j < 4; ++j)
      bb.u[j] = (q2[2 * j].x >> 16) | (q2[2 * j + 1].x & 0xffff0000u);
    accm[1] = __builtin_amdgcn_mfma_f32_16x16x32_bf16(af, bb.s, cz, 0, 0, 0);
    // ib2: lows of .y
    #pragma unroll
    for (int j = 0; j < 4; ++j)
      bb.u[j] = (q2[2 * j].y & 0xffffu) | (q2[2 * j + 1].y << 16);
    accm[2] = __builtin_amdgcn_mfma_f32_16x16x32_bf16(af, bb.s, cz, 0, 0, 0);
    // ib3: highs of .y
    #pragma unroll
    for (int j = 0; j < 4; ++j)
      bb.u[j] = (q2[2 * j].y >> 16) | (q2[2 * j + 1].y & 0xffff0000u);
    accm[3] = __builtin_amdgcn_mfma_f32_16x16x32_bf16(af, bb.s, cz, 0, 0, 0);
    // stage M as bf16 into swizzled Mb
    #pragma unroll
    for (int ib = 0; ib < 4; ++ib)
      #pragma unroll
      for (int r = 0; r < 4; ++r) {
        const int g = l4 * 4 + r;
        const u32 k = (u32)(g * 64 + ib * 16 + l15);
        u32 byt = (u32)m * 2048u + k * 2u;
        byt ^= ((u32)((m & 7) ^ (g & 7)) << 4);
        *(u16*)(smem + MB_OFF + byt) = rbf(accm[ib][r]);
      }
  }
  __syncthreads();   // Mb complete (cross-wave); also orders W reads before Rb writes

  // ---- split-k GEMM2: wave (pairp, half) computes partial over ks = half*16..+15 ----
  f32x4 acc = {0.f, 0.f, 0.f, 0.f};
  {
    const u32 rowb = (u32)l15 * 2048u;
    const u32 swl = (u32)(l15 & 7) << 4;
    #pragma unroll 8
    for (int j = 0; j < 16; ++j) {
      const int ks = half * 16 + j;
      const u32 kc = (u32)ks * 32u + (u32)l4 * 8u;
      const u32 g7 = (((kc >> 6) & 7u) << 4);
      const u32 byt = (rowb + kc * 2u) ^ swl ^ g7;
      const short8 a2 = *(const short8*)(smem + MB_OFF + byt);
      const short8 b2 = *(const short8*)(k2f + ((u32)(ks * 4 + pairp) * 64u + (u32)lane) * 8u);
      acc = __builtin_amdgcn_mfma_f32_16x16x32_bf16(a2, b2, acc, 0, 0, 0);
    }
  }

  // ---- split-k reduction through Rb (aliases dead W region) ----
  if (half == 1) {
    #pragma unroll
    for (int r = 0; r < 4; ++r) {
      const int row = l4 * 4 + r;
      const u32 byt = (u32)pairp * 1024u + (u32)row * 64u + (u32)((l15 ^ l4) * 4);
      *(float*)(smem + RB_OFF + byt) = acc[r];
    }
  }
  __syncthreads();
  if (half == 0) {
    #pragma unroll
    for (int r = 0; r < 4; ++r) {
      const int row = l4 * 4 + r;
      const u32 byt = (u32)pairp * 1024u + (u32)row * 64u + (u32)((l15 ^ l4) * 4);
      acc[r] += *(const float*)(smem + RB_OFF + byt);
    }
    const int o = pairp * 16 + l15;
    const float bv = bias[o];
    #pragma unroll
    for (int r = 0; r < 4; ++r)
      out[(n0 + l4 * 4 + r) * CH + o] = acc[r] * (1.0f / 32.0f) + bv;
  }
}

extern "C" void kernel_launch(void* const* d_in, const int* in_sizes, int n_in,
                              void* d_out, int out_size, void* d_ws, size_t ws_size,
                              hipStream_t stream) {
  const float* features = (const float*)d_in[0];
  const int* receivers  = (const int*)d_in[1];
  const float* relpos   = (const float*)d_in[2];
  const float* wsup     = (const float*)d_in[3];
  const int* aptr       = (const int*)d_in[4];
  const float* kern     = (const float*)d_in[5];
  const float* bias     = (const float*)d_in[6];
  float* out = (float*)d_out;

  const int N = in_sizes[0] / CH;   // 50000
  u16* fbf = (u16*)d_ws;                                    // N*64 bf16, interleaved
  u16* k2f = (u16*)((char*)d_ws + (size_t)N * CH * 2);      // 128 KB, frag-ordered

  const int nq = N * 16;                                    // qwords of fbf
  const int prep_total = nq + 65536;
  prep_all<<<dim3((prep_total + 255) / 256), dim3(256), 0, stream>>>(
      features, fbf, kern, k2f, nq);

  cconv_main<<<dim3(N / TM), dim3(THREADS), 0, stream>>>(
      receivers, relpos, wsup, aptr, fbf, k2f, bias, out);
}